// Round 3
// baseline (119.534 us; speedup 1.0000x reference)
//
#include <hip/hip_runtime.h>
#include <math.h>

// Problem constants (fixed by the reference file)
constexpr int B  = 1024;
constexpr int NL = 64;
constexpr int W  = 2048;
constexpr int INNER = NL - 2;            // layers 1..62 inclusive -> 62 layers
constexpr float EPS_N = 1e-8f;
constexpr float EPS_Y = 1e-9f;

typedef float v2f __attribute__((ext_vector_type(2)));

static __device__ __forceinline__ v2f v2(float x) { return (v2f){x, x}; }

// FOUR wavelengths per thread as two independent packed pairs, with a fully
// PACKED polynomial sincos replacing v_sin/v_cos. rocprof fit showed the
// hardware trans ops cost ~14-16 cy each (wave64) and were ~70% of VALUBusy;
// the poly runs on the full-rate v_pk_* pipe and never leaves v2f form, so
// the scalar-trans pair-packing movs disappear too.
//
// sincos(2*pi*phi) for phi in revolutions, phi in [0.025, 1.375]:
//   t   = phi - rint(phi)             in [-0.5, 0.5]
//   sh2 = 2*sin(pi*t)  (odd poly, deg 11, arg <= pi/2, err ~1e-7)
//   ch  =   cos(pi*t)  (even poly, deg 12, err ~7e-9)
//   s   = sin(2*pi*phi) = sh2*ch
//   c   = cos(2*pi*phi) = 1 - 0.5*sh2^2
//
// Transfer matrix M = [[a, i*b],[i*c, d]] tracked as packed real quads:
//   a' = a*c + b*(n*s);  b' = b*c - a*(s/n)
//   c' = c*c - d*(n*s);  d' = d*c + c*(s/n)
__global__ __launch_bounds__(256)
void tmm_kernel(const float* __restrict__ n_layers,
                const float* __restrict__ d_layers,
                const float* __restrict__ wavelengths,
                float* __restrict__ out)
{
    __shared__ float4 s_layer[INNER][2];   // [i][0]=(nd,nd,n,n) [i][1]=(rc,rc,0,0)
    __shared__ float  s_edge[2];           // n_in, n_sub

    const int b   = blockIdx.y;
    const int tid = threadIdx.x;
    const int w0  = blockIdx.x * 1024 + tid * 4;

    if (tid < INNER) {
        const float n  = n_layers[b * NL + 1 + tid];
        const float d  = d_layers[b * NL + 1 + tid];
        const float nd = n * d;
        const float rc = 1.0f / (n + EPS_N);
        s_layer[tid][0] = make_float4(nd, nd, n, n);
        s_layer[tid][1] = make_float4(rc, rc, 0.0f, 0.0f);
    }
    if (tid == INNER) {
        s_edge[0] = n_layers[b * NL];                      // n_in
        s_edge[1] = n_layers[b * NL + NL - 1];             // n_sub
    }
    __syncthreads();

    const float4 wl = *(const float4*)&wavelengths[w0];
    const v2f invl0 = { 1.0f / wl.x, 1.0f / wl.y };        // k0 in revolutions
    const v2f invl1 = { 1.0f / wl.z, 1.0f / wl.w };

    // sin(pi*t)*2 odd-poly coeffs (Taylor, trunc err ~1.1e-7 at |t|=0.5)
    const v2f S0 = v2( 6.2831853071795865f);
    const v2f S1 = v2(-10.335425560099940f);
    const v2f S2 = v2( 5.1003280550379037f);
    const v2f S3 = v2(-1.1985290900808722f);
    const v2f S4 = v2( 0.16429178162694839f);
    const v2f S5 = v2(-0.014740862219505272f);
    // cos(pi*t) even-poly coeffs (trunc err ~6.4e-9)
    const v2f C1 = v2(-4.9348022005446793f);
    const v2f C2 = v2( 4.0587121264167682f);
    const v2f C3 = v2(-1.3352627688545895f);
    const v2f C4 = v2( 0.23533063035889320f);
    const v2f C5 = v2(-0.025806891390014061f);
    const v2f C6 = v2( 0.0019295743094039231f);
    const v2f ONE  = v2(1.0f);
    const v2f NHALF = v2(-0.5f);

    v2f av0 = {1.0f, 1.0f}, bv0 = {0.0f, 0.0f}, cv0 = {0.0f, 0.0f}, dv0 = {1.0f, 1.0f};
    v2f av1 = {1.0f, 1.0f}, bv1 = {0.0f, 0.0f}, cv1 = {0.0f, 0.0f}, dv1 = {1.0f, 1.0f};

    #pragma unroll
    for (int i = 0; i < INNER; ++i) {
        const float4 A  = s_layer[i][0];                   // ds_read_b128 (uniform bcast)
        const float2 Rr = *(const float2*)&s_layer[i][1];  // ds_read_b64
        const v2f nd2 = {A.x, A.y};
        const v2f nn2 = {A.z, A.w};
        const v2f rr2 = {Rr.x, Rr.y};

        // ---- packed phases ----
        const v2f ph0 = nd2 * invl0;
        const v2f ph1 = nd2 * invl1;

        // ---- packed sincos, chain 0 ----
        v2f j0; j0.x = __builtin_rintf(ph0.x); j0.y = __builtin_rintf(ph0.y);
        const v2f t0 = ph0 - j0;
        const v2f y0 = t0 * t0;
        v2f p0 = __builtin_elementwise_fma(y0, S5, S4);
        p0 = __builtin_elementwise_fma(y0, p0, S3);
        p0 = __builtin_elementwise_fma(y0, p0, S2);
        p0 = __builtin_elementwise_fma(y0, p0, S1);
        p0 = __builtin_elementwise_fma(y0, p0, S0);
        const v2f sh0 = t0 * p0;                           // 2*sin(pi*t)
        v2f q0 = __builtin_elementwise_fma(y0, C6, C5);
        q0 = __builtin_elementwise_fma(y0, q0, C4);
        q0 = __builtin_elementwise_fma(y0, q0, C3);
        q0 = __builtin_elementwise_fma(y0, q0, C2);
        q0 = __builtin_elementwise_fma(y0, q0, C1);
        const v2f chh0 = __builtin_elementwise_fma(y0, q0, ONE);   // cos(pi*t)
        const v2f s0 = sh0 * chh0;                         // sin(2*pi*phi)
        const v2f c0 = __builtin_elementwise_fma(sh0 * sh0, NHALF, ONE); // cos

        // ---- packed sincos, chain 1 ----
        v2f j1; j1.x = __builtin_rintf(ph1.x); j1.y = __builtin_rintf(ph1.y);
        const v2f t1 = ph1 - j1;
        const v2f y1 = t1 * t1;
        v2f p1 = __builtin_elementwise_fma(y1, S5, S4);
        p1 = __builtin_elementwise_fma(y1, p1, S3);
        p1 = __builtin_elementwise_fma(y1, p1, S2);
        p1 = __builtin_elementwise_fma(y1, p1, S1);
        p1 = __builtin_elementwise_fma(y1, p1, S0);
        const v2f sh1 = t1 * p1;
        v2f q1 = __builtin_elementwise_fma(y1, C6, C5);
        q1 = __builtin_elementwise_fma(y1, q1, C4);
        q1 = __builtin_elementwise_fma(y1, q1, C3);
        q1 = __builtin_elementwise_fma(y1, q1, C2);
        q1 = __builtin_elementwise_fma(y1, q1, C1);
        const v2f chh1 = __builtin_elementwise_fma(y1, q1, ONE);
        const v2f s1 = sh1 * chh1;
        const v2f c1 = __builtin_elementwise_fma(sh1 * sh1, NHALF, ONE);

        // ---- matrix updates ----
        const v2f ns0 = nn2 * s0;
        const v2f sn0 = rr2 * s0;
        const v2f ns1 = nn2 * s1;
        const v2f sn1 = rr2 * s1;

        const v2f an0 = __builtin_elementwise_fma(bv0,  ns0, av0 * c0);
        const v2f bn0 = __builtin_elementwise_fma(-av0, sn0, bv0 * c0);
        const v2f cn0 = __builtin_elementwise_fma(-dv0, ns0, cv0 * c0);
        const v2f dn0 = __builtin_elementwise_fma(cv0,  sn0, dv0 * c0);
        const v2f an1 = __builtin_elementwise_fma(bv1,  ns1, av1 * c1);
        const v2f bn1 = __builtin_elementwise_fma(-av1, sn1, bv1 * c1);
        const v2f cn1 = __builtin_elementwise_fma(-dv1, ns1, cv1 * c1);
        const v2f dn1 = __builtin_elementwise_fma(cv1,  sn1, dv1 * c1);
        av0 = an0; bv0 = bn0; cv0 = cn0; dv0 = dn0;
        av1 = an1; bv1 = bn1; cv1 = cn1; dv1 = dn1;
    }

    const float n_in  = s_edge[0];
    const float n_sub = s_edge[1];

    // E = a + eps_Y + i*(b*n_sub);  H = d*n_sub + i*c;  R = |nE-H|^2 / |nE+H|^2
    float4 Rout;
    {
        const float Er = av0.x + EPS_Y, Ei = bv0.x * n_sub;
        const float Hr = dv0.x * n_sub, Hi = cv0.x;
        const float Nr = fmaf(n_in, Er, -Hr), Ni = fmaf(n_in, Ei, -Hi);
        const float Dr = fmaf(n_in, Er,  Hr), Di = fmaf(n_in, Ei,  Hi);
        Rout.x = (Nr * Nr + Ni * Ni) / (Dr * Dr + Di * Di);
    }
    {
        const float Er = av0.y + EPS_Y, Ei = bv0.y * n_sub;
        const float Hr = dv0.y * n_sub, Hi = cv0.y;
        const float Nr = fmaf(n_in, Er, -Hr), Ni = fmaf(n_in, Ei, -Hi);
        const float Dr = fmaf(n_in, Er,  Hr), Di = fmaf(n_in, Ei,  Hi);
        Rout.y = (Nr * Nr + Ni * Ni) / (Dr * Dr + Di * Di);
    }
    {
        const float Er = av1.x + EPS_Y, Ei = bv1.x * n_sub;
        const float Hr = dv1.x * n_sub, Hi = cv1.x;
        const float Nr = fmaf(n_in, Er, -Hr), Ni = fmaf(n_in, Ei, -Hi);
        const float Dr = fmaf(n_in, Er,  Hr), Di = fmaf(n_in, Ei,  Hi);
        Rout.z = (Nr * Nr + Ni * Ni) / (Dr * Dr + Di * Di);
    }
    {
        const float Er = av1.y + EPS_Y, Ei = bv1.y * n_sub;
        const float Hr = dv1.y * n_sub, Hi = cv1.y;
        const float Nr = fmaf(n_in, Er, -Hr), Ni = fmaf(n_in, Ei, -Hi);
        const float Dr = fmaf(n_in, Er,  Hr), Di = fmaf(n_in, Ei,  Hi);
        Rout.w = (Nr * Nr + Ni * Ni) / (Dr * Dr + Di * Di);
    }
    *(float4*)&out[b * W + w0] = Rout;     // coalesced 16B/lane store
}

extern "C" void kernel_launch(void* const* d_in, const int* in_sizes, int n_in,
                              void* d_out, int out_size, void* d_ws, size_t ws_size,
                              hipStream_t stream)
{
    const float* n_layers    = (const float*)d_in[0];
    const float* d_layers    = (const float*)d_in[1];
    const float* wavelengths = (const float*)d_in[2];
    float* out = (float*)d_out;

    dim3 grid(W / 1024, B);                // 4 wavelengths per thread
    dim3 block(256);
    tmm_kernel<<<grid, block, 0, stream>>>(n_layers, d_layers, wavelengths, out);
}

// Round 4
// 102.907 us; speedup vs baseline: 1.1616x; 1.1616x over previous
//
#include <hip/hip_runtime.h>
#include <math.h>

// Problem constants (fixed by the reference file)
constexpr int B  = 1024;
constexpr int NL = 64;
constexpr int W  = 2048;
constexpr int INNER = NL - 2;            // layers 1..62 inclusive -> 62 layers
constexpr float EPS_N = 1e-8f;
constexpr float EPS_Y = 1e-9f;

// FOUR wavelengths per thread, honestly SCALAR code.
//
// Evidence from rounds 0-3 busy-cycle fits: hipcc scalarizes all float2
// ext-vector fp32 ops (no v_pk_*_f32 emitted), and on gfx950 packed fp32 is
// same-FLOP-rate anyway (advertised FP32 peak 157.3 TF == scalar SIMD-32
// rate), so the packed forms were pure fiction. The per-wl-layer floor is
// 11 fp32 ops + 2 quarter-rate trans = ~38 busy cy/wave, which round 2
// already achieved at 68% VALUBusy. This version targets the 32% idle:
//  - one ds_read_b128 per layer (nd, n, rc, pad) instead of b128+b64
//  - no vector-type operand copies
//  - __launch_bounds__(256, 8): keeps the 8 waves/SIMD we need for full
//    residency (2048 WGs = 8 blocks/CU exactly) while raising the VGPR cap
//    to 64 (compiler previously squeezed to 24, limiting how far it could
//    hoist LDS reads / schedule trans across the unrolled 62 iterations).
//
// Transfer matrix M = [[a, i*b],[i*c, d]] stays real:
//   a' = a*c + b*(n*s);  b' = b*c - a*(s/n)
//   c' = c*c - d*(n*s);  d' = d*c + c*(s/n)
// phi tracked in REVOLUTIONS so v_sin_f32/v_cos_f32 need no pre-scaling.
__global__ __launch_bounds__(256, 8)
void tmm_kernel(const float* __restrict__ n_layers,
                const float* __restrict__ d_layers,
                const float* __restrict__ wavelengths,
                float* __restrict__ out)
{
    __shared__ float4 s_layer[INNER];      // (n*d, n, 1/(n+eps), 0)
    __shared__ float  s_edge[2];           // n_in, n_sub

    const int b   = blockIdx.y;
    const int tid = threadIdx.x;
    const int w0  = blockIdx.x * 1024 + tid * 4;

    if (tid < INNER) {
        const float n = n_layers[b * NL + 1 + tid];
        const float d = d_layers[b * NL + 1 + tid];
        s_layer[tid] = make_float4(n * d, n, 1.0f / (n + EPS_N), 0.0f);
    }
    if (tid == INNER) {
        s_edge[0] = n_layers[b * NL];                      // n_in
        s_edge[1] = n_layers[b * NL + NL - 1];             // n_sub
    }
    __syncthreads();

    const float4 wl = *(const float4*)&wavelengths[w0];
    float il[4] = { 1.0f / wl.x, 1.0f / wl.y, 1.0f / wl.z, 1.0f / wl.w };

    float a[4]  = {1.0f, 1.0f, 1.0f, 1.0f};
    float bm[4] = {0.0f, 0.0f, 0.0f, 0.0f};
    float cm[4] = {0.0f, 0.0f, 0.0f, 0.0f};
    float d[4]  = {1.0f, 1.0f, 1.0f, 1.0f};

    #pragma unroll
    for (int i = 0; i < INNER; ++i) {
        const float4 L = s_layer[i];       // one ds_read_b128, wave-uniform bcast
        #pragma unroll
        for (int k = 0; k < 4; ++k) {
            const float ph = L.x * il[k];                  // phase in revolutions
            const float s  = __builtin_amdgcn_sinf(ph);    // v_sin_f32
            const float c  = __builtin_amdgcn_cosf(ph);    // v_cos_f32
            const float ns = L.y * s;                      // n*s
            const float sn = L.z * s;                      // s/(n+eps)

            const float an = fmaf(bm[k],  ns, a[k]  * c);
            const float bn = fmaf(a[k],  -sn, bm[k] * c);
            const float cn = fmaf(d[k],  -ns, cm[k] * c);
            const float dn = fmaf(cm[k],  sn, d[k]  * c);
            a[k] = an; bm[k] = bn; cm[k] = cn; d[k] = dn;
        }
    }

    const float n_in  = s_edge[0];
    const float n_sub = s_edge[1];

    // E = a + eps_Y + i*(b*n_sub);  H = d*n_sub + i*c;  R = |nE-H|^2 / |nE+H|^2
    float r[4];
    #pragma unroll
    for (int k = 0; k < 4; ++k) {
        const float Er = a[k] + EPS_Y;
        const float Ei = bm[k] * n_sub;
        const float Hr = d[k] * n_sub;
        const float Hi = cm[k];
        const float Nr = fmaf(n_in, Er, -Hr), Ni = fmaf(n_in, Ei, -Hi);
        const float Dr = fmaf(n_in, Er,  Hr), Di = fmaf(n_in, Ei,  Hi);
        r[k] = (Nr * Nr + Ni * Ni) / (Dr * Dr + Di * Di);
    }
    *(float4*)&out[b * W + w0] = make_float4(r[0], r[1], r[2], r[3]);
}

extern "C" void kernel_launch(void* const* d_in, const int* in_sizes, int n_in,
                              void* d_out, int out_size, void* d_ws, size_t ws_size,
                              hipStream_t stream)
{
    const float* n_layers    = (const float*)d_in[0];
    const float* d_layers    = (const float*)d_in[1];
    const float* wavelengths = (const float*)d_in[2];
    float* out = (float*)d_out;

    dim3 grid(W / 1024, B);                // 4 wavelengths per thread, 8 blocks/CU
    dim3 block(256);
    tmm_kernel<<<grid, block, 0, stream>>>(n_layers, d_layers, wavelengths, out);
}

// Round 5
// 99.192 us; speedup vs baseline: 1.2051x; 1.0375x over previous
//
#include <hip/hip_runtime.h>
#include <math.h>

// Problem constants (fixed by the reference file)
constexpr int B  = 1024;
constexpr int NL = 64;
constexpr int W  = 2048;
constexpr int INNER = NL - 2;            // layers 1..62 inclusive -> 62 layers
constexpr float EPS_N = 1e-8f;
constexpr float EPS_Y = 1e-9f;

// ---------------------------------------------------------------------------
// Round-5 structure: layer constants go through the SCALAR pipe, not LDS.
//
// Evidence: round 2's busy cycles are exactly its op count (4wl x 11 ALU x 2cy
// + 8 trans x 8cy ~= 155 cy/wave-iter); the missing 32% is all 8 lockstep
// waves/SIMD co-stalling on the same ds_read s_waitcnt each layer. Round 4's
// indexed arrays spilled to scratch (WRITE_SIZE 8 -> 45 MB) - named scalars
// only here.
//
// Fix: a tiny prep kernel writes per-batch wave-UNIFORM records
//   ws[b*64 + i]     = (n*d, n, 1/(n+eps), 0)      i = 0..61
//   ws[b*64 + INNER] = (n_in, n_sub, 0, 0)
// The main kernel reads them via const __restrict__ at uniform addresses ->
// s_load_dwordx4 into SGPRs, prefetched far ahead by the scalar unit (offsets
// are compile-time after full unroll). No LDS, no __syncthreads, and each
// VALU consumer reads its single SGPR operand directly (1-SGPR rule OK):
//   ph = s_nd * v_il ; ns = s_n * v_s ; sn = s_rc * v_s
// Transfer matrix M = [[a, i*b],[i*c, d]] stays real:
//   a' = a*c + b*(n*s);  b' = b*c - a*(s/n)
//   c' = c*c - d*(n*s);  d' = d*c + c*(s/n)
// phi tracked in REVOLUTIONS (v_sin_f32/v_cos_f32 semantics).
// ---------------------------------------------------------------------------

__global__ __launch_bounds__(64)
void prep_kernel(const float* __restrict__ n_layers,
                 const float* __restrict__ d_layers,
                 float4* __restrict__ ws)
{
    const int b = blockIdx.x;
    const int i = threadIdx.x;
    if (i < INNER) {
        const float n = n_layers[b * NL + 1 + i];
        const float d = d_layers[b * NL + 1 + i];
        ws[b * 64 + i] = make_float4(n * d, n, 1.0f / (n + EPS_N), 0.0f);
    } else if (i == INNER) {
        ws[b * 64 + INNER] =
            make_float4(n_layers[b * NL], n_layers[b * NL + NL - 1], 0.0f, 0.0f);
    }
}

__global__ __launch_bounds__(256)
void tmm_kernel(const float4* __restrict__ lw,
                const float* __restrict__ wavelengths,
                float* __restrict__ out)
{
    const int b   = blockIdx.y;
    const int tid = threadIdx.x;
    const int w0  = blockIdx.x * 1024 + tid * 4;
    const float4* __restrict__ Lb = lw + b * 64;   // uniform base -> SMEM path

    const float4 wl = *(const float4*)&wavelengths[w0];
    const float il0 = 1.0f / wl.x;
    const float il1 = 1.0f / wl.y;
    const float il2 = 1.0f / wl.z;
    const float il3 = 1.0f / wl.w;

    // Named scalars ONLY (round-4 lesson: indexed arrays -> scratch spill).
    float a0 = 1.f, bb0 = 0.f, cc0 = 0.f, dd0 = 1.f;
    float a1 = 1.f, bb1 = 0.f, cc1 = 0.f, dd1 = 1.f;
    float a2 = 1.f, bb2 = 0.f, cc2 = 0.f, dd2 = 1.f;
    float a3 = 1.f, bb3 = 0.f, cc3 = 0.f, dd3 = 1.f;

#define STEP(k)                                                     \
    {                                                               \
        const float ph = L.x * il##k;   /* s_nd * v_il   */         \
        const float s  = __builtin_amdgcn_sinf(ph);                 \
        const float c  = __builtin_amdgcn_cosf(ph);                 \
        const float ns = L.y * s;       /* s_n  * v_s    */         \
        const float sn = L.z * s;       /* s_rc * v_s    */         \
        const float an = fmaf(bb##k,  ns, a##k  * c);               \
        const float bn = fmaf(a##k,  -sn, bb##k * c);               \
        const float cn = fmaf(dd##k, -ns, cc##k * c);               \
        const float dn = fmaf(cc##k,  sn, dd##k * c);               \
        a##k = an; bb##k = bn; cc##k = cn; dd##k = dn;              \
    }

    #pragma unroll
    for (int i = 0; i < INNER; ++i) {
        const float4 L = Lb[i];          // uniform addr -> s_load_dwordx4
        STEP(0)
        STEP(1)
        STEP(2)
        STEP(3)
    }
#undef STEP

    const float4 Eg  = Lb[INNER];        // (n_in, n_sub, 0, 0) via s_load
    const float n_in  = Eg.x;
    const float n_sub = Eg.y;

    // E = a + eps_Y + i*(b*n_sub);  H = d*n_sub + i*c;  R = |nE-H|^2/|nE+H|^2
    float4 R;
#define EPI(k, slot)                                                \
    {                                                               \
        const float Er = a##k + EPS_Y;                              \
        const float Ei = bb##k * n_sub;                             \
        const float Hr = dd##k * n_sub;                             \
        const float Hi = cc##k;                                     \
        const float Nr = fmaf(n_in, Er, -Hr);                       \
        const float Ni = fmaf(n_in, Ei, -Hi);                       \
        const float Dr = fmaf(n_in, Er,  Hr);                       \
        const float Di = fmaf(n_in, Ei,  Hi);                       \
        slot = (Nr * Nr + Ni * Ni) / (Dr * Dr + Di * Di);           \
    }
    EPI(0, R.x)
    EPI(1, R.y)
    EPI(2, R.z)
    EPI(3, R.w)
#undef EPI

    *(float4*)&out[b * W + w0] = R;      // coalesced 16B/lane store
}

extern "C" void kernel_launch(void* const* d_in, const int* in_sizes, int n_in,
                              void* d_out, int out_size, void* d_ws, size_t ws_size,
                              hipStream_t stream)
{
    const float* n_layers    = (const float*)d_in[0];
    const float* d_layers    = (const float*)d_in[1];
    const float* wavelengths = (const float*)d_in[2];
    float* out = (float*)d_out;
    float4* ws = (float4*)d_ws;          // needs B*64*16 = 1 MiB of workspace

    prep_kernel<<<dim3(B), dim3(64), 0, stream>>>(n_layers, d_layers, ws);

    dim3 grid(W / 1024, B);              // 4 wavelengths/thread, 8 blocks/CU
    dim3 block(256);
    tmm_kernel<<<grid, block, 0, stream>>>(ws, wavelengths, out);
}

// Round 6
// 98.210 us; speedup vs baseline: 1.2171x; 1.0100x over previous
//
#include <hip/hip_runtime.h>
#include <math.h>

// Problem constants (fixed by the reference file)
constexpr int B  = 1024;
constexpr int NL = 64;
constexpr int W  = 2048;
constexpr int INNER = NL - 2;            // layers 1..62 inclusive -> 62 layers
constexpr float EPS_N = 1e-8f;
constexpr float EPS_Y = 1e-9f;

// ---------------------------------------------------------------------------
// Round-6 structure: ZERO in-loop memory. Layer constants live in VGPR lanes,
// broadcast per-iteration with v_readlane_b32 (compile-time lane index).
//
// Evidence trail: rounds 2/5 both sit at busy ~150 cy/wave-iter (= op floor:
// 44 ALU x 2cy + 8 trans x 8cy) with ~80 cy/iter idle that survived both the
// LDS path (ds_read ~120cy) and the scalar path (s_load ~200cy) -- the idle
// is in-loop memory latency the compiler can't prefetch deep enough to hide
// (VGPR/SGPR budget), and lockstep waves co-stall on the same waitcnt.
//
// Here: lane L holds layer L's (n, d) loaded ONCE (coalesced, L2-resident);
// nd = n*d and rc = 1/(n+eps) computed per lane. The unrolled loop reads
//   s_nd = v_readlane(v_nd, i+1); s_n = v_readlane(v_n, i+1); s_rc = ...
// -- register-only, no vmcnt/lgkmcnt in all 62 iterations. Lane 0 gives
// n_in, lane 63 gives n_sub. No LDS, no barrier, no prep kernel/workspace.
// Each nd*il / n*s / rc*s uses exactly one SGPR operand (1-SGPR rule OK).
//
// Transfer matrix M = [[a, i*b],[i*c, d]] stays real:
//   a' = a*c + b*(n*s);  b' = b*c - a*(s/n)
//   c' = c*c - d*(n*s);  d' = d*c + c*(s/n)
// phi tracked in REVOLUTIONS (v_sin_f32/v_cos_f32 take revolutions).
// Named scalars only (round-4 lesson: indexed arrays -> scratch).
// ---------------------------------------------------------------------------

static __device__ __forceinline__ float bcast_lane(float v, int lane)
{
    return __uint_as_float(__builtin_amdgcn_readlane(__float_as_uint(v), lane));
}

__global__ __launch_bounds__(256)
void tmm_kernel(const float* __restrict__ n_layers,
                const float* __restrict__ d_layers,
                const float* __restrict__ wavelengths,
                float* __restrict__ out)
{
    const int b    = blockIdx.y;
    const int tid  = threadIdx.x;
    const int lane = tid & 63;
    const int w0   = blockIdx.x * 1024 + tid * 4;

    // One-time per-lane layer record: lane L <- layer L of batch b.
    const float n_l  = n_layers[b * NL + lane];
    const float d_l  = d_layers[b * NL + lane];
    const float nd_l = n_l * d_l;
    const float rc_l = 1.0f / (n_l + EPS_N);

    const float4 wl = *(const float4*)&wavelengths[w0];
    const float il0 = 1.0f / wl.x;
    const float il1 = 1.0f / wl.y;
    const float il2 = 1.0f / wl.z;
    const float il3 = 1.0f / wl.w;

    float a0 = 1.f, bb0 = 0.f, cc0 = 0.f, dd0 = 1.f;
    float a1 = 1.f, bb1 = 0.f, cc1 = 0.f, dd1 = 1.f;
    float a2 = 1.f, bb2 = 0.f, cc2 = 0.f, dd2 = 1.f;
    float a3 = 1.f, bb3 = 0.f, cc3 = 0.f, dd3 = 1.f;

#define STEP(k)                                                     \
    {                                                               \
        const float ph = nd * il##k;    /* sgpr * vgpr */           \
        const float s  = __builtin_amdgcn_sinf(ph);                 \
        const float c  = __builtin_amdgcn_cosf(ph);                 \
        const float ns = nn * s;        /* sgpr * vgpr */           \
        const float sn = rc * s;        /* sgpr * vgpr */           \
        const float an = fmaf(bb##k,  ns, a##k  * c);               \
        const float bn = fmaf(a##k,  -sn, bb##k * c);               \
        const float cn = fmaf(dd##k, -ns, cc##k * c);               \
        const float dn = fmaf(cc##k,  sn, dd##k * c);               \
        a##k = an; bb##k = bn; cc##k = cn; dd##k = dn;              \
    }

    #pragma unroll
    for (int i = 0; i < INNER; ++i) {
        const float nd = bcast_lane(nd_l, i + 1);   // v_readlane_b32, imm lane
        const float nn = bcast_lane(n_l,  i + 1);
        const float rc = bcast_lane(rc_l, i + 1);
        STEP(0)
        STEP(1)
        STEP(2)
        STEP(3)
    }
#undef STEP

    const float n_in  = bcast_lane(n_l, 0);
    const float n_sub = bcast_lane(n_l, NL - 1);

    // E = a + eps_Y + i*(b*n_sub);  H = d*n_sub + i*c;  R = |nE-H|^2/|nE+H|^2
    float4 R;
#define EPI(k, slot)                                                \
    {                                                               \
        const float Er = a##k + EPS_Y;                              \
        const float Ei = bb##k * n_sub;                             \
        const float Hr = dd##k * n_sub;                             \
        const float Hi = cc##k;                                     \
        const float Nr = fmaf(n_in, Er, -Hr);                       \
        const float Ni = fmaf(n_in, Ei, -Hi);                       \
        const float Dr = fmaf(n_in, Er,  Hr);                       \
        const float Di = fmaf(n_in, Ei,  Hi);                       \
        slot = (Nr * Nr + Ni * Ni) / (Dr * Dr + Di * Di);           \
    }
    EPI(0, R.x)
    EPI(1, R.y)
    EPI(2, R.z)
    EPI(3, R.w)
#undef EPI

    *(float4*)&out[b * W + w0] = R;      // coalesced 16B/lane store
}

extern "C" void kernel_launch(void* const* d_in, const int* in_sizes, int n_in,
                              void* d_out, int out_size, void* d_ws, size_t ws_size,
                              hipStream_t stream)
{
    const float* n_layers    = (const float*)d_in[0];
    const float* d_layers    = (const float*)d_in[1];
    const float* wavelengths = (const float*)d_in[2];
    float* out = (float*)d_out;

    dim3 grid(W / 1024, B);              // 4 wavelengths/thread, 8 blocks/CU
    dim3 block(256);
    tmm_kernel<<<grid, block, 0, stream>>>(n_layers, d_layers, wavelengths, out);
}